// Round 1
// baseline (2652.311 us; speedup 1.0000x reference)
//
#include <hip/hip_runtime.h>
#include <math.h>

#define BATCH_N  8192
#define IN_SIZE_N 512
#define HIDDEN_N 2048
#define HEADS_N   64
#define RANK_N    16

// ---------------------------------------------------------------------------
// Generic f32 tiled GEMM:  C[M,N] = act( A[M,K] @ B[K,N] + bias )
//   BT=false: B0 is B[K,N] row-major.
//   BT=true : B-operand given as Bt[N,K] row-major, split across two pointers:
//             rows [0,split) from B0, rows [split, split+b1_rows) from B1
//             (rows beyond are clamped -> harmless padding compute).
//   SQA     : square A elements while staging (for the diag GEMM on h^2).
//   ACT     : epilogue tanh(x + bias[n]).
// 256 threads, 16x16 thread grid, per-thread micro-tile TM x TN.
// LDS rows padded +4 floats to keep staging stores ~conflict-free.
// ---------------------------------------------------------------------------
template<int BM, int BN, bool BT, bool SQA, bool ACT>
__global__ __launch_bounds__(256)
void gemm_f32(const float* __restrict__ A,
              const float* __restrict__ B0,
              const float* __restrict__ B1,
              int split, int b1_rows,
              const float* __restrict__ bias,
              float* __restrict__ C,
              int M, int N, int K)
{
    constexpr int BK = 16;
    constexpr int TM = BM / 16;
    constexpr int TN = BN / 16;
    constexpr int LDA = BM + 4;
    constexpr int LDB = BN + 4;
    __shared__ float As[BK][LDA];
    __shared__ float Bs[BK][LDB];

    const int tid = threadIdx.x;
    const int bn = blockIdx.x;
    const int bm = blockIdx.y;
    const int tr = tid >> 4;   // 0..15  (row group)
    const int tc = tid & 15;   // 0..15  (col group)

    float acc[TM][TN];
#pragma unroll
    for (int i = 0; i < TM; ++i)
#pragma unroll
        for (int j = 0; j < TN; ++j) acc[i][j] = 0.0f;

    for (int k0 = 0; k0 < K; k0 += BK) {
        // ---- stage A tile (BM x BK), transposed into As[k][m]
        constexpr int AV = BM * BK / 4;    // float4 count
#pragma unroll
        for (int v = tid; v < AV; v += 256) {
            const int row = v >> 2;            // 4 float4 per row (BK=16)
            const int cv  = (v & 3) * 4;
            float4 x = *(const float4*)(A + (size_t)(bm * BM + row) * K + k0 + cv);
            if (SQA) { x.x *= x.x; x.y *= x.y; x.z *= x.z; x.w *= x.w; }
            As[cv + 0][row] = x.x;
            As[cv + 1][row] = x.y;
            As[cv + 2][row] = x.z;
            As[cv + 3][row] = x.w;
        }
        // ---- stage B tile
        if (!BT) {
            constexpr int BV  = BK * BN / 4;
            constexpr int RPV = BN / 4;        // float4 per row
#pragma unroll
            for (int v = tid; v < BV; v += 256) {
                const int row = v / RPV;
                const int cv  = (v % RPV) * 4;
                float4 x = *(const float4*)(B0 + (size_t)(k0 + row) * N + bn * BN + cv);
                *(float4*)&Bs[row][cv] = x;
            }
        } else {
            constexpr int BV = BN * BK / 4;
#pragma unroll
            for (int v = tid; v < BV; v += 256) {
                const int row = v >> 2;        // n within tile
                const int cv  = (v & 3) * 4;
                const int n = bn * BN + row;
                const float* src;
                if (n < split) {
                    src = B0 + (size_t)n * K;
                } else {
                    int n2 = n - split;
                    if (n2 >= b1_rows) n2 = b1_rows - 1;   // clamp padding rows
                    src = B1 + (size_t)n2 * K;
                }
                float4 x = *(const float4*)(src + k0 + cv);
                Bs[cv + 0][row] = x.x;
                Bs[cv + 1][row] = x.y;
                Bs[cv + 2][row] = x.z;
                Bs[cv + 3][row] = x.w;
            }
        }
        __syncthreads();
#pragma unroll
        for (int kk = 0; kk < BK; ++kk) {
            float a[TM], b[TN];
            *(float4*)&a[0] = *(const float4*)&As[kk][tr * TM];
            if constexpr (TM == 8)
                *(float4*)&a[4] = *(const float4*)&As[kk][tr * TM + 4];
            // split column groups {tc*4, BN/2 + tc*4}: 16B stride across lanes
            // -> 2-way bank aliasing (free) instead of 4-way at stride 32B
            *(float4*)&b[0] = *(const float4*)&Bs[kk][tc * 4];
            if constexpr (TN == 8)
                *(float4*)&b[4] = *(const float4*)&Bs[kk][BN / 2 + tc * 4];
#pragma unroll
            for (int i = 0; i < TM; ++i)
#pragma unroll
                for (int j = 0; j < TN; ++j)
                    acc[i][j] = fmaf(a[i], b[j], acc[i][j]);
        }
        __syncthreads();
    }

    // ---- epilogue
#pragma unroll
    for (int i = 0; i < TM; ++i) {
        const int m = bm * BM + tr * TM + i;
        float* Crow = C + (size_t)m * N + bn * BN;
#pragma unroll
        for (int jg = 0; jg < TN / 4; ++jg) {
            const int ncol = jg * (BN / 2) + tc * 4;
            float4 v;
            v.x = acc[i][jg * 4 + 0];
            v.y = acc[i][jg * 4 + 1];
            v.z = acc[i][jg * 4 + 2];
            v.w = acc[i][jg * 4 + 3];
            if (ACT) {
                const float* bp = bias + bn * BN + ncol;
                v.x = tanhf(v.x + bp[0]);
                v.y = tanhf(v.y + bp[1]);
                v.z = tanhf(v.z + bp[2]);
                v.w = tanhf(v.w + bp[3]);
            }
            *(float4*)&Crow[ncol] = v;
        }
    }
}

// Vsq[h,d] = sum_r fm_V[h,r,d]^2
__global__ __launch_bounds__(256)
void fm_vsq(const float* __restrict__ V, float* __restrict__ Vsq)
{
    const int h = blockIdx.x;
    for (int d = threadIdx.x; d < HIDDEN_N; d += 256) {
        float s = 0.0f;
#pragma unroll
        for (int r = 0; r < RANK_N; ++r) {
            const float v = V[((size_t)h * RANK_N + r) * HIDDEN_N + d];
            s = fmaf(v, v, s);
        }
        Vsq[(size_t)h * HIDDEN_N + d] = s;
    }
}

// out[h,b] = w0[h] + P[b,h] + 0.5*( sum_r P[b,64+16h+r]^2 - D[b,h] )
__global__ __launch_bounds__(256)
void fm_combine(const float* __restrict__ P,   // [BATCH, 1152]
                const float* __restrict__ D,   // [BATCH, 64]
                const float* __restrict__ w0,  // [64]
                float* __restrict__ out)       // [64, BATCH]
{
    const int b = blockIdx.x * 256 + threadIdx.x;
    const float* Pb = P + (size_t)b * 1152;
    const float* Db = D + (size_t)b * 64;
#pragma unroll 4
    for (int h = 0; h < HEADS_N; ++h) {
        float q = 0.0f;
#pragma unroll
        for (int rv = 0; rv < 4; ++rv) {
            const float4 v = *(const float4*)&Pb[64 + h * 16 + rv * 4];
            q = fmaf(v.x, v.x, q); q = fmaf(v.y, v.y, q);
            q = fmaf(v.z, v.z, q); q = fmaf(v.w, v.w, q);
        }
        out[(size_t)h * BATCH_N + b] = w0[h] + Pb[h] + 0.5f * (q - Db[h]);
    }
}

extern "C" void kernel_launch(void* const* d_in, const int* in_sizes, int n_in,
                              void* d_out, int out_size, void* d_ws, size_t ws_size,
                              hipStream_t stream)
{
    const float* x   = (const float*)d_in[0];
    const float* W1  = (const float*)d_in[1];
    const float* b1  = (const float*)d_in[2];
    const float* W2  = (const float*)d_in[3];
    const float* b2  = (const float*)d_in[4];
    const float* W3  = (const float*)d_in[5];
    const float* b3  = (const float*)d_in[6];
    const float* fw0 = (const float*)d_in[7];
    const float* fw  = (const float*)d_in[8];
    const float* fV  = (const float*)d_in[9];
    float* out = (float*)d_out;

    // workspace layout (128 MB total, buffers reused):
    //   hA [0,64MB)      : h1, then h3
    //   hB [64,128MB)    : h2, then P[8192,1152] (37.75MB) | Vsq | D
    char* ws = (char*)d_ws;
    float* hA  = (float*)ws;
    float* hB  = (float*)(ws + 67108864ull);
    float* P   = hB;
    float* Vsq = (float*)(ws + 104857600ull);   // right after P
    float* Dg  = (float*)(ws + 105381888ull);

    const dim3 blk(256, 1, 1);

    // h1 = tanh(x @ W1 + b1)
    gemm_f32<128,128,false,false,true><<<dim3(HIDDEN_N/128, BATCH_N/128), blk, 0, stream>>>(
        x, W1, nullptr, 1 << 30, 1, b1, hA, BATCH_N, HIDDEN_N, IN_SIZE_N);
    // h2 = tanh(h1 @ W2 + b2)
    gemm_f32<128,128,false,false,true><<<dim3(HIDDEN_N/128, BATCH_N/128), blk, 0, stream>>>(
        hA, W2, nullptr, 1 << 30, 1, b2, hB, BATCH_N, HIDDEN_N, HIDDEN_N);
    // h3 = tanh(h2 @ W3 + b3)   (overwrites h1)
    gemm_f32<128,128,false,false,true><<<dim3(HIDDEN_N/128, BATCH_N/128), blk, 0, stream>>>(
        hB, W3, nullptr, 1 << 30, 1, b3, hA, BATCH_N, HIDDEN_N, HIDDEN_N);

    // Vsq[h,d] = sum_r V^2
    fm_vsq<<<dim3(HEADS_N), blk, 0, stream>>>(fV, Vsq);

    // P[b, 0:64]      = lin (h3 . fm_w rows)
    // P[b, 64+16h+r]  = vx  (h3 . fm_V rows)   N padded 1088 -> 1152
    gemm_f32<128,128,true,false,false><<<dim3(1152/128, BATCH_N/128), blk, 0, stream>>>(
        hA, fw, fV, HEADS_N, HEADS_N * RANK_N, nullptr, P, BATCH_N, 1152, HIDDEN_N);

    // D[b,h] = h3^2 . Vsq rows
    gemm_f32<64,64,true,true,false><<<dim3(1, BATCH_N/64), blk, 0, stream>>>(
        hA, Vsq, nullptr, 1 << 30, 1, nullptr, Dg, BATCH_N, HEADS_N, HIDDEN_N);

    fm_combine<<<dim3(BATCH_N/256), blk, 0, stream>>>(P, Dg, fw0, out);
}

// Round 2
// 1033.078 us; speedup vs baseline: 2.5674x; 2.5674x over previous
//
#include <hip/hip_runtime.h>
#include <math.h>

#define BATCH_N   8192
#define IN_SIZE_N  512
#define HIDDEN_N  2048
#define HEADS_N     64
#define RANK_N      16
#define PN        1152   // padded FM-head GEMM width: 64 lin + 1024 vx + 64 pad

typedef short s16x4 __attribute__((ext_vector_type(4)));
typedef short s16x8 __attribute__((ext_vector_type(8)));
typedef float f32x4 __attribute__((ext_vector_type(4)));
typedef unsigned int u32;

__device__ __forceinline__ short f2bf(float f) {
    __bf16 b = (__bf16)f; short r; __builtin_memcpy(&r, &b, 2); return r;
}
__device__ __forceinline__ float bf2f(short s) {
    __bf16 b; __builtin_memcpy(&b, &s, 2); return (float)b;
}
__device__ __forceinline__ void gld16(const void* g, void* l) {
    __builtin_amdgcn_global_load_lds(
        (const __attribute__((address_space(1))) u32*)g,
        (__attribute__((address_space(3))) u32*)l, 16, 0, 0);
}

// ---------------------------------------------------------------------------
// Split-bf16 MFMA GEMM: C = act(A @ Bt^T + bias), A=[M][K] hi/lo bf16,
// Bt=[N][K] hi/lo bf16. 128x128 tile, BK=32, 4 waves (2x2), m97 structure.
// ACT: tanh(x+bias) epilogue, writes hi/lo bf16 pair. !ACT: writes f32.
// ---------------------------------------------------------------------------
template<bool ACT>
__global__ __launch_bounds__(256)
void gemm_mfma(const short* __restrict__ Ahi, const short* __restrict__ Alo,
               const short* __restrict__ Bhi, const short* __restrict__ Blo,
               const float* __restrict__ bias,
               short* __restrict__ Chi, short* __restrict__ Clo,
               float* __restrict__ Cf,
               int M, int N, int K)
{
    __shared__ __align__(16) short sAh[128 * 32];
    __shared__ __align__(16) short sAl[128 * 32];
    __shared__ __align__(16) short sBh[128 * 32];
    __shared__ __align__(16) short sBl[128 * 32];

    const int tid  = threadIdx.x;
    const int lane = tid & 63;
    const int wave = tid >> 6;
    const int wr = wave >> 1, wc = wave & 1;
    const int l15 = lane & 15, ks = lane >> 4;
    const int bn = blockIdx.x, bm = blockIdx.y;

    // staging: per array, 8 segments of 64 x 16B chunks; wave w owns segs w and w+4
    const int c0 = wave * 64 + lane, c1 = (wave + 4) * 64 + lane;
    const size_t g0 = (size_t)(c0 >> 2) * K + (size_t)(c0 & 3) * 8;
    const size_t g1 = (size_t)(c1 >> 2) * K + (size_t)(c1 & 3) * 8;
    const int l0 = wave * 512, l1 = (wave + 4) * 512;   // LDS element offsets

    const short* aH = Ahi + (size_t)bm * 128 * K;
    const short* aL = Alo + (size_t)bm * 128 * K;
    const short* bH = Bhi + (size_t)bn * 128 * K;
    const short* bL = Blo + (size_t)bn * 128 * K;

    int aoff[4], boff[4];
#pragma unroll
    for (int m = 0; m < 4; ++m) aoff[m] = (wr * 64 + m * 16 + l15) * 32 + ks * 8;
#pragma unroll
    for (int n = 0; n < 4; ++n) boff[n] = (wc * 64 + n * 16 + l15) * 32 + ks * 8;

    f32x4 acc[4][4] = {};

#pragma unroll 1
    for (int k0 = 0; k0 < K; k0 += 32) {
        gld16(aH + g0 + k0, &sAh[l0]);
        gld16(aH + g1 + k0, &sAh[l1]);
        gld16(aL + g0 + k0, &sAl[l0]);
        gld16(aL + g1 + k0, &sAl[l1]);
        gld16(bH + g0 + k0, &sBh[l0]);
        gld16(bH + g1 + k0, &sBh[l1]);
        gld16(bL + g0 + k0, &sBl[l0]);
        gld16(bL + g1 + k0, &sBl[l1]);
        __syncthreads();

        s16x8 bhv[4], blv[4];
#pragma unroll
        for (int n = 0; n < 4; ++n) {
            bhv[n] = *(const s16x8*)&sBh[boff[n]];
            blv[n] = *(const s16x8*)&sBl[boff[n]];
        }
#pragma unroll
        for (int m = 0; m < 4; ++m) {
            const s16x8 ah = *(const s16x8*)&sAh[aoff[m]];
            const s16x8 al = *(const s16x8*)&sAl[aoff[m]];
#pragma unroll
            for (int n = 0; n < 4; ++n) {
                acc[m][n] = __builtin_amdgcn_mfma_f32_16x16x32_bf16(ah, bhv[n], acc[m][n], 0, 0, 0);
                acc[m][n] = __builtin_amdgcn_mfma_f32_16x16x32_bf16(ah, blv[n], acc[m][n], 0, 0, 0);
                acc[m][n] = __builtin_amdgcn_mfma_f32_16x16x32_bf16(al, bhv[n], acc[m][n], 0, 0, 0);
            }
        }
        __syncthreads();
    }

    const int row0 = bm * 128 + wr * 64;
    const int col0 = bn * 128 + wc * 64;
#pragma unroll
    for (int n = 0; n < 4; ++n) {
        const int col = col0 + n * 16 + l15;
        float bv = 0.0f;
        if constexpr (ACT) bv = bias[col];
#pragma unroll
        for (int m = 0; m < 4; ++m) {
#pragma unroll
            for (int j = 0; j < 4; ++j) {
                const int row = row0 + m * 16 + ks * 4 + j;
                float v = acc[m][n][j];
                if constexpr (ACT) {
                    v = tanhf(v + bv);
                    const short h = f2bf(v);
                    Chi[(size_t)row * N + col] = h;
                    Clo[(size_t)row * N + col] = f2bf(v - bf2f(h));
                } else {
                    Cf[(size_t)row * N + col] = v;
                }
            }
        }
    }
}

// f32 src -> hi/lo bf16 split (grid-stride, float4). Elements >= n_src -> 0.
__global__ __launch_bounds__(256)
void pack_split(const float* __restrict__ src, long n_src,
                short* __restrict__ hi, short* __restrict__ lo, long n_total)
{
    const long stride = (long)gridDim.x * 1024;
    for (long i4 = ((long)blockIdx.x * 256 + threadIdx.x) * 4; i4 < n_total; i4 += stride) {
        float a[4] = {0.f, 0.f, 0.f, 0.f};
        if (i4 < n_src) {
            const float4 v = *(const float4*)&src[i4];
            a[0] = v.x; a[1] = v.y; a[2] = v.z; a[3] = v.w;
        }
        s16x4 h, l;
#pragma unroll
        for (int j = 0; j < 4; ++j) {
            h[j] = f2bf(a[j]);
            l[j] = f2bf(a[j] - bf2f(h[j]));
        }
        *(s16x4*)&hi[i4] = h;
        *(s16x4*)&lo[i4] = l;
    }
}

// W[K][N] f32 -> Thi/Tlo[N][K] bf16. Block (32,8), 32x32 LDS tile.
__global__ __launch_bounds__(256)
void transpose_split(const float* __restrict__ W,
                     short* __restrict__ Thi, short* __restrict__ Tlo,
                     int K, int N)
{
    __shared__ float t[32][33];
    const int tx = threadIdx.x, ty = threadIdx.y;
    const int n0 = blockIdx.x * 32, k0 = blockIdx.y * 32;
#pragma unroll
    for (int i = 0; i < 4; ++i)
        t[ty * 4 + i][tx] = W[(size_t)(k0 + ty * 4 + i) * N + n0 + tx];
    __syncthreads();
#pragma unroll
    for (int i = 0; i < 4; ++i) {
        const int n = n0 + ty * 4 + i;
        const float v = t[tx][ty * 4 + i];
        const short h = f2bf(v);
        Thi[(size_t)n * K + k0 + tx] = h;
        Tlo[(size_t)n * K + k0 + tx] = f2bf(v - bf2f(h));
    }
}

// Vsq[h][d] = sum_r V[h][r][d]^2
__global__ __launch_bounds__(256)
void fm_vsq(const float* __restrict__ V, float* __restrict__ Vsq)
{
    const int h = blockIdx.x;
    for (int d = threadIdx.x; d < HIDDEN_N; d += 256) {
        float s = 0.0f;
#pragma unroll
        for (int r = 0; r < RANK_N; ++r) {
            const float v = V[((size_t)h * RANK_N + r) * HIDDEN_N + d];
            s = fmaf(v, v, s);
        }
        Vsq[(size_t)h * HIDDEN_N + d] = s;
    }
}

// D[m][64] = (h3[m].^2) @ Vsq^T ; A from hi/lo bf16, 32x64 tile, BK=16
__global__ __launch_bounds__(256)
void gemm_diag(const short* __restrict__ Ahi, const short* __restrict__ Alo,
               const float* __restrict__ Vsq, float* __restrict__ D, int K)
{
    __shared__ float As[16][36];
    __shared__ float Bs[16][68];
    const int tid = threadIdx.x;
    const int tr = tid >> 4, tc = tid & 15;
    const int bm = blockIdx.x;
    float acc[2][4] = {};
    for (int k0 = 0; k0 < K; k0 += 16) {
        if (tid < 128) {
            const int row = tid >> 2, cv = (tid & 3) * 4;
            const size_t off = (size_t)(bm * 32 + row) * K + k0 + cv;
            const s16x4 h = *(const s16x4*)&Ahi[off];
            const s16x4 l = *(const s16x4*)&Alo[off];
#pragma unroll
            for (int j = 0; j < 4; ++j) {
                const float f = bf2f(h[j]) + bf2f(l[j]);
                As[cv + j][row] = f * f;
            }
        }
        {
            const int row = tid >> 2, cv = (tid & 3) * 4;
            const float4 v = *(const float4*)&Vsq[(size_t)row * K + k0 + cv];
            Bs[cv + 0][row] = v.x; Bs[cv + 1][row] = v.y;
            Bs[cv + 2][row] = v.z; Bs[cv + 3][row] = v.w;
        }
        __syncthreads();
#pragma unroll
        for (int kk = 0; kk < 16; ++kk) {
            const float a0 = As[kk][tr * 2], a1 = As[kk][tr * 2 + 1];
            const float4 b = *(const float4*)&Bs[kk][tc * 4];
            acc[0][0] = fmaf(a0, b.x, acc[0][0]); acc[0][1] = fmaf(a0, b.y, acc[0][1]);
            acc[0][2] = fmaf(a0, b.z, acc[0][2]); acc[0][3] = fmaf(a0, b.w, acc[0][3]);
            acc[1][0] = fmaf(a1, b.x, acc[1][0]); acc[1][1] = fmaf(a1, b.y, acc[1][1]);
            acc[1][2] = fmaf(a1, b.z, acc[1][2]); acc[1][3] = fmaf(a1, b.w, acc[1][3]);
        }
        __syncthreads();
    }
#pragma unroll
    for (int i = 0; i < 2; ++i)
#pragma unroll
        for (int j = 0; j < 4; ++j)
            D[(size_t)(bm * 32 + tr * 2 + i) * 64 + tc * 4 + j] = acc[i][j];
}

// out[h, boff+b] = w0[h] + P[b,h] + 0.5*(sum_r P[b,64+16h+r]^2 - D[b,h])
__global__ __launch_bounds__(256)
void fm_combine(const float* __restrict__ P, const float* __restrict__ D,
                const float* __restrict__ w0, float* __restrict__ out, int boff)
{
    const int b = blockIdx.x * 256 + threadIdx.x;
    const float* Pb = P + (size_t)b * PN;
    const float* Db = D + (size_t)b * 64;
#pragma unroll 4
    for (int h = 0; h < HEADS_N; ++h) {
        float q = 0.0f;
#pragma unroll
        for (int rv = 0; rv < 4; ++rv) {
            const float4 v = *(const float4*)&Pb[64 + h * 16 + rv * 4];
            q = fmaf(v.x, v.x, q); q = fmaf(v.y, v.y, q);
            q = fmaf(v.z, v.z, q); q = fmaf(v.w, v.w, q);
        }
        out[(size_t)h * BATCH_N + boff + b] = w0[h] + Pb[h] + 0.5f * (q - Db[h]);
    }
}

extern "C" void kernel_launch(void* const* d_in, const int* in_sizes, int n_in,
                              void* d_out, int out_size, void* d_ws, size_t ws_size,
                              hipStream_t stream)
{
    const float* x   = (const float*)d_in[0];
    const float* W1  = (const float*)d_in[1];
    const float* b1  = (const float*)d_in[2];
    const float* W2  = (const float*)d_in[3];
    const float* b2  = (const float*)d_in[4];
    const float* W3  = (const float*)d_in[5];
    const float* b3  = (const float*)d_in[6];
    const float* fw0 = (const float*)d_in[7];
    const float* fw  = (const float*)d_in[8];
    const float* fV  = (const float*)d_in[9];
    float* out = (float*)d_out;

    // chunked over batch to fit ws (proven ws >= ~107.5 MB from R1)
    const int nchunk = (ws_size >= 115000000ull) ? 2 : 4;
    const int CH = BATCH_N / nchunk;

    char* ws = (char*)d_ws;
    size_t o = 0;
    auto alloc = [&](size_t bytes) { void* p = ws + o; o += (bytes + 255) & ~(size_t)255; return p; };

    short* W1h = (short*)alloc((size_t)HIDDEN_N * IN_SIZE_N * 2);
    short* W1l = (short*)alloc((size_t)HIDDEN_N * IN_SIZE_N * 2);
    short* W2h = (short*)alloc((size_t)HIDDEN_N * HIDDEN_N * 2);
    short* W2l = (short*)alloc((size_t)HIDDEN_N * HIDDEN_N * 2);
    short* W3h = (short*)alloc((size_t)HIDDEN_N * HIDDEN_N * 2);
    short* W3l = (short*)alloc((size_t)HIDDEN_N * HIDDEN_N * 2);
    short* PBh = (short*)alloc((size_t)PN * HIDDEN_N * 2);
    short* PBl = (short*)alloc((size_t)PN * HIDDEN_N * 2);
    float* Vsq = (float*)alloc((size_t)HEADS_N * HIDDEN_N * 4);
    short* hAh = (short*)alloc((size_t)CH * HIDDEN_N * 2);
    short* hAl = (short*)alloc((size_t)CH * HIDDEN_N * 2);
    char*  hBb = (char*) alloc((size_t)CH * HIDDEN_N * 4);   // hBh+hBl contiguous
    short* hBh = (short*)hBb;
    short* hBl = hBh + (size_t)CH * HIDDEN_N;
    short* xh  = (short*)hBb;                      // alias (dead when h2/P live)
    short* xl  = xh + (size_t)CH * IN_SIZE_N;
    float* P   = (float*)hBb;                      // [CH][PN] f32, alias of hB
    float* Dg  = (float*)(hBb + (size_t)CH * PN * 4);

    const dim3 blk(256, 1, 1);

    // one-time packs
    transpose_split<<<dim3(HIDDEN_N / 32, IN_SIZE_N / 32), dim3(32, 8), 0, stream>>>(W1, W1h, W1l, IN_SIZE_N, HIDDEN_N);
    transpose_split<<<dim3(HIDDEN_N / 32, HIDDEN_N / 32), dim3(32, 8), 0, stream>>>(W2, W2h, W2l, HIDDEN_N, HIDDEN_N);
    transpose_split<<<dim3(HIDDEN_N / 32, HIDDEN_N / 32), dim3(32, 8), 0, stream>>>(W3, W3h, W3l, HIDDEN_N, HIDDEN_N);
    pack_split<<<dim3(128), blk, 0, stream>>>(fw, (long)HEADS_N * HIDDEN_N, PBh, PBl, (long)HEADS_N * HIDDEN_N);
    pack_split<<<dim3(1024), blk, 0, stream>>>(fV, (long)HEADS_N * RANK_N * HIDDEN_N,
                                               PBh + (size_t)HEADS_N * HIDDEN_N,
                                               PBl + (size_t)HEADS_N * HIDDEN_N,
                                               (long)(PN - HEADS_N) * HIDDEN_N);
    fm_vsq<<<dim3(HEADS_N), blk, 0, stream>>>(fV, Vsq);

    for (int c = 0; c < nchunk; ++c) {
        pack_split<<<dim3(1024), blk, 0, stream>>>(x + (size_t)c * CH * IN_SIZE_N,
                                                   (long)CH * IN_SIZE_N, xh, xl, (long)CH * IN_SIZE_N);
        gemm_mfma<true><<<dim3(HIDDEN_N / 128, CH / 128), blk, 0, stream>>>(
            xh, xl, W1h, W1l, b1, hAh, hAl, nullptr, CH, HIDDEN_N, IN_SIZE_N);
        gemm_mfma<true><<<dim3(HIDDEN_N / 128, CH / 128), blk, 0, stream>>>(
            hAh, hAl, W2h, W2l, b2, hBh, hBl, nullptr, CH, HIDDEN_N, HIDDEN_N);
        gemm_mfma<true><<<dim3(HIDDEN_N / 128, CH / 128), blk, 0, stream>>>(
            hBh, hBl, W3h, W3l, b3, hAh, hAl, nullptr, CH, HIDDEN_N, HIDDEN_N);
        gemm_mfma<false><<<dim3(PN / 128, CH / 128), blk, 0, stream>>>(
            hAh, hAl, PBh, PBl, nullptr, nullptr, nullptr, P, CH, PN, HIDDEN_N);
        gemm_diag<<<dim3(CH / 32), blk, 0, stream>>>(hAh, hAl, Vsq, Dg, HIDDEN_N);
        fm_combine<<<dim3(CH / 256), blk, 0, stream>>>(P, Dg, fw0, out, c * CH);
    }
}

// Round 3
// 936.731 us; speedup vs baseline: 2.8315x; 1.1029x over previous
//
#include <hip/hip_runtime.h>
#include <math.h>

#define BATCH_N   8192
#define IN_SIZE_N  512
#define HIDDEN_N  2048
#define HEADS_N     64
#define RANK_N      16
#define PN        1152   // padded FM-head GEMM width: 64 lin + 1024 vx + 64 pad

typedef short s16x4 __attribute__((ext_vector_type(4)));
typedef short s16x8 __attribute__((ext_vector_type(8)));
typedef float f32x4 __attribute__((ext_vector_type(4)));
typedef unsigned int u32;

__device__ __forceinline__ short f2bf(float f) {
    __bf16 b = (__bf16)f; short r; __builtin_memcpy(&r, &b, 2); return r;
}
__device__ __forceinline__ float bf2f(short s) {
    __bf16 b; __builtin_memcpy(&b, &s, 2); return (float)b;
}
__device__ __forceinline__ void gld16(const void* g, void* l) {
    __builtin_amdgcn_global_load_lds(
        (const __attribute__((address_space(1))) u32*)g,
        (__attribute__((address_space(3))) u32*)l, 16, 0, 0);
}

// ---------------------------------------------------------------------------
// Split-bf16 MFMA GEMM, 8-phase-style counted-vmcnt pipeline.
// C = act(A @ Bt^T + bias); A=[M][K] hi/lo bf16, Bt=[N][K] hi/lo bf16.
// Tile BM x 128, BK=32, 512 threads (8 waves, 2M x 4N), TRIPLE-buffered
// K-tiles in LDS: while computing tile t, stage tile t+2 (6 gld) into the
// slot freed by t-1; per-K-tile boundary waits vmcnt(6) (never 0).
// LDS layout linear (global_load_lds); bank-conflict-free frag reads via
// source-side XOR swizzle: logical (row,ks) chunk stored at index
// row*4 + (ks ^ (row&3)).
// ---------------------------------------------------------------------------
template<int BM, bool ACT>
__global__ __launch_bounds__(512)
void gemm8(const short* __restrict__ Ahi, const short* __restrict__ Alo,
           const short* __restrict__ Bhi, const short* __restrict__ Blo,
           const float* __restrict__ bias,
           short* __restrict__ Chi, short* __restrict__ Clo,
           float* __restrict__ Cf,
           int GX, int N, int K)
{
    constexpr int BN = 128;
    constexpr int MF = BM / 32;              // M-frags per wave (8 or 4)
    constexpr int MPP = MF / 4;              // M-frags per phase (2 or 1)
    constexpr int NG = (BM == 256) ? 6 : 4;  // gld issues per K-tile
    constexpr int AH = 0;
    constexpr int AL = BM * 32;
    constexpr int BH = 2 * BM * 32;
    constexpr int BL = 2 * BM * 32 + BN * 32;
    constexpr int SBUF = 2 * BM * 32 + 2 * BN * 32;
    __shared__ __align__(16) short lds[3 * SBUF];

    const int tid = threadIdx.x;
    const int lane = tid & 63, wave = tid >> 6;
    const int wr = wave >> 2, wc = wave & 3;
    const int l15 = lane & 15, ks = lane >> 4;

    // XCD-aware swizzle (gridDim.x % 8 == 0 for all our launches)
    const int flat = blockIdx.x;
    const int wg = (flat & 7) * (gridDim.x >> 3) + (flat >> 3);
    const int bn = wg % GX, bm = wg / GX;

    const short* Ab_h = Ahi + (size_t)bm * BM * K;
    const short* Ab_l = Alo + (size_t)bm * BM * K;
    const short* Bb_h = Bhi + (size_t)bn * BN * K;
    const short* Bb_l = Blo + (size_t)bn * BN * K;

    // staging: chunk c -> row=c>>2, ks_src=(c&3)^(row&3); LDS linear at c*16B
    const int rA0 = tid >> 2, kA0 = (tid & 3) ^ (rA0 & 3);
    const size_t sA0 = (size_t)rA0 * K + kA0 * 8;
    const size_t sA1 = sA0 + (size_t)128 * K;     // chunk tid+512 (BM=256)
    const size_t sB  = sA0;                       // B rows 0..127, same formula
    const int d0 = (tid & ~63) * 8;               // wave-uniform LDS el offset
    const int d1 = d0 + 512 * 8;

    // frag read offsets: el = row*32 + ((ks ^ (row&3))<<3); row&3 == lane&3
    const int ksx = (ks ^ (lane & 3)) << 3;
    int aoff[MF], boff[2];
#pragma unroll
    for (int m = 0; m < MF; ++m)
        aoff[m] = (wr * (BM / 2) + m * 16 + l15) * 32 + ksx;
#pragma unroll
    for (int n = 0; n < 2; ++n)
        boff[n] = (wc * 32 + n * 16 + l15) * 32 + ksx;

    f32x4 acc[MF][2] = {};
    const int NT = K >> 5;

    auto issue = [&](int g, short* nb, int k2) {
        if constexpr (BM == 256) {
            switch (g) {
            case 0: gld16(Ab_h + sA0 + k2, &nb[AH + d0]); break;
            case 1: gld16(Ab_h + sA1 + k2, &nb[AH + d1]); break;
            case 2: gld16(Ab_l + sA0 + k2, &nb[AL + d0]); break;
            case 3: gld16(Ab_l + sA1 + k2, &nb[AL + d1]); break;
            case 4: gld16(Bb_h + sB  + k2, &nb[BH + d0]); break;
            case 5: gld16(Bb_l + sB  + k2, &nb[BL + d0]); break;
            }
        } else {
            switch (g) {
            case 0: gld16(Ab_h + sA0 + k2, &nb[AH + d0]); break;
            case 1: gld16(Ab_l + sA0 + k2, &nb[AL + d0]); break;
            case 2: gld16(Bb_h + sB  + k2, &nb[BH + d0]); break;
            case 3: gld16(Bb_l + sB  + k2, &nb[BL + d0]); break;
            }
        }
    };

    // prologue: stage tiles 0 and 1; wait tile0 (leave tile1 in flight)
#pragma unroll
    for (int g = 0; g < NG; ++g) issue(g, &lds[0], 0);
#pragma unroll
    for (int g = 0; g < NG; ++g) issue(g, &lds[SBUF], 32);
    if constexpr (BM == 256) asm volatile("s_waitcnt vmcnt(6)" ::: "memory");
    else                     asm volatile("s_waitcnt vmcnt(4)" ::: "memory");
    __builtin_amdgcn_s_barrier();

    int slot = 0, islot = 2;
#pragma unroll 1
    for (int t = 0; t < NT; ++t) {
        short* buf = &lds[slot * SBUF];
        short* nb  = &lds[islot * SBUF];
        const bool valid = (t + 2 < NT);
        const int k2 = (t + 2) << 5;
        s16x8 bh[2], bl[2];
#pragma unroll
        for (int p = 0; p < 4; ++p) {
            if (p == 0) {
#pragma unroll
                for (int n = 0; n < 2; ++n) {
                    bh[n] = *(const s16x8*)&buf[BH + boff[n]];
                    bl[n] = *(const s16x8*)&buf[BL + boff[n]];
                }
            }
            s16x8 ah[MPP], al[MPP];
#pragma unroll
            for (int i = 0; i < MPP; ++i) {
                ah[i] = *(const s16x8*)&buf[AH + aoff[p * MPP + i]];
                al[i] = *(const s16x8*)&buf[AL + aoff[p * MPP + i]];
            }
            if (valid) {
#pragma unroll
                for (int g = p * 2; g < p * 2 + 2; ++g)
                    if (g < NG) issue(g, nb, k2);
            }
            __builtin_amdgcn_s_barrier();
            asm volatile("s_waitcnt lgkmcnt(0)" ::: "memory");
            __builtin_amdgcn_sched_barrier(0);
            __builtin_amdgcn_s_setprio(1);
#pragma unroll
            for (int i = 0; i < MPP; ++i) {
                const int m = p * MPP + i;
#pragma unroll
                for (int n = 0; n < 2; ++n) {
                    acc[m][n] = __builtin_amdgcn_mfma_f32_16x16x32_bf16(ah[i], bh[n], acc[m][n], 0, 0, 0);
                    acc[m][n] = __builtin_amdgcn_mfma_f32_16x16x32_bf16(ah[i], bl[n], acc[m][n], 0, 0, 0);
                    acc[m][n] = __builtin_amdgcn_mfma_f32_16x16x32_bf16(al[i], bh[n], acc[m][n], 0, 0, 0);
                }
            }
            __builtin_amdgcn_s_setprio(0);
            __builtin_amdgcn_sched_barrier(0);
            if (p == 3) {
                if (valid) {
                    if constexpr (BM == 256) asm volatile("s_waitcnt vmcnt(6)" ::: "memory");
                    else                     asm volatile("s_waitcnt vmcnt(4)" ::: "memory");
                } else {
                    asm volatile("s_waitcnt vmcnt(0)" ::: "memory");
                }
            }
            __builtin_amdgcn_s_barrier();
        }
        slot  = (slot  == 2) ? 0 : slot + 1;
        islot = (islot == 2) ? 0 : islot + 1;
    }

    // epilogue (C/D map: col = lane&15, row = (lane>>4)*4 + j)
    const int row0 = bm * BM + wr * (BM / 2);
    const int col0 = bn * BN + wc * 32;
#pragma unroll
    for (int n = 0; n < 2; ++n) {
        const int col = col0 + n * 16 + l15;
        float bv = 0.0f;
        if constexpr (ACT) bv = bias[col];
#pragma unroll
        for (int m = 0; m < MF; ++m) {
#pragma unroll
            for (int j = 0; j < 4; ++j) {
                const int row = row0 + m * 16 + ks * 4 + j;
                float v = acc[m][n][j];
                if constexpr (ACT) {
                    v = tanhf(v + bv);
                    const short h = f2bf(v);
                    Chi[(size_t)row * N + col] = h;
                    Clo[(size_t)row * N + col] = f2bf(v - bf2f(h));
                } else {
                    Cf[(size_t)row * N + col] = v;
                }
            }
        }
    }
}

// f32 src -> hi/lo bf16 split (grid-stride, float4). Elements >= n_src -> 0.
__global__ __launch_bounds__(256)
void pack_split(const float* __restrict__ src, long n_src,
                short* __restrict__ hi, short* __restrict__ lo, long n_total)
{
    const long stride = (long)gridDim.x * 1024;
    for (long i4 = ((long)blockIdx.x * 256 + threadIdx.x) * 4; i4 < n_total; i4 += stride) {
        float a[4] = {0.f, 0.f, 0.f, 0.f};
        if (i4 < n_src) {
            const float4 v = *(const float4*)&src[i4];
            a[0] = v.x; a[1] = v.y; a[2] = v.z; a[3] = v.w;
        }
        s16x4 h, l;
#pragma unroll
        for (int j = 0; j < 4; ++j) {
            h[j] = f2bf(a[j]);
            l[j] = f2bf(a[j] - bf2f(h[j]));
        }
        *(s16x4*)&hi[i4] = h;
        *(s16x4*)&lo[i4] = l;
    }
}

// W[K][N] f32 -> Thi/Tlo[N][K] bf16. Block (32,8), 32x32 LDS tile.
__global__ __launch_bounds__(256)
void transpose_split(const float* __restrict__ W,
                     short* __restrict__ Thi, short* __restrict__ Tlo,
                     int K, int N)
{
    __shared__ float t[32][33];
    const int tx = threadIdx.x, ty = threadIdx.y;
    const int n0 = blockIdx.x * 32, k0 = blockIdx.y * 32;
#pragma unroll
    for (int i = 0; i < 4; ++i)
        t[ty * 4 + i][tx] = W[(size_t)(k0 + ty * 4 + i) * N + n0 + tx];
    __syncthreads();
#pragma unroll
    for (int i = 0; i < 4; ++i) {
        const int n = n0 + ty * 4 + i;
        const float v = t[tx][ty * 4 + i];
        const short h = f2bf(v);
        Thi[(size_t)n * K + k0 + tx] = h;
        Tlo[(size_t)n * K + k0 + tx] = f2bf(v - bf2f(h));
    }
}

// Vsq[h][d] = sum_r V[h][r][d]^2
__global__ __launch_bounds__(256)
void fm_vsq(const float* __restrict__ V, float* __restrict__ Vsq)
{
    const int h = blockIdx.x;
    for (int d = threadIdx.x; d < HIDDEN_N; d += 256) {
        float s = 0.0f;
#pragma unroll
        for (int r = 0; r < RANK_N; ++r) {
            const float v = V[((size_t)h * RANK_N + r) * HIDDEN_N + d];
            s = fmaf(v, v, s);
        }
        Vsq[(size_t)h * HIDDEN_N + d] = s;
    }
}

// D[m][64] = (h3[m].^2) @ Vsq^T ; A from hi/lo bf16, 32x64 tile, BK=16
__global__ __launch_bounds__(256)
void gemm_diag(const short* __restrict__ Ahi, const short* __restrict__ Alo,
               const float* __restrict__ Vsq, float* __restrict__ D, int K)
{
    __shared__ float As[16][36];
    __shared__ float Bs[16][68];
    const int tid = threadIdx.x;
    const int tr = tid >> 4, tc = tid & 15;
    const int bm = blockIdx.x;
    float acc[2][4] = {};
    for (int k0 = 0; k0 < K; k0 += 16) {
        if (tid < 128) {
            const int row = tid >> 2, cv = (tid & 3) * 4;
            const size_t off = (size_t)(bm * 32 + row) * K + k0 + cv;
            const s16x4 h = *(const s16x4*)&Ahi[off];
            const s16x4 l = *(const s16x4*)&Alo[off];
#pragma unroll
            for (int j = 0; j < 4; ++j) {
                const float f = bf2f(h[j]) + bf2f(l[j]);
                As[cv + j][row] = f * f;
            }
        }
        {
            const int row = tid >> 2, cv = (tid & 3) * 4;
            const float4 v = *(const float4*)&Vsq[(size_t)row * K + k0 + cv];
            Bs[cv + 0][row] = v.x; Bs[cv + 1][row] = v.y;
            Bs[cv + 2][row] = v.z; Bs[cv + 3][row] = v.w;
        }
        __syncthreads();
#pragma unroll
        for (int kk = 0; kk < 16; ++kk) {
            const float a0 = As[kk][tr * 2], a1 = As[kk][tr * 2 + 1];
            const float4 b = *(const float4*)&Bs[kk][tc * 4];
            acc[0][0] = fmaf(a0, b.x, acc[0][0]); acc[0][1] = fmaf(a0, b.y, acc[0][1]);
            acc[0][2] = fmaf(a0, b.z, acc[0][2]); acc[0][3] = fmaf(a0, b.w, acc[0][3]);
            acc[1][0] = fmaf(a1, b.x, acc[1][0]); acc[1][1] = fmaf(a1, b.y, acc[1][1]);
            acc[1][2] = fmaf(a1, b.z, acc[1][2]); acc[1][3] = fmaf(a1, b.w, acc[1][3]);
        }
        __syncthreads();
    }
#pragma unroll
    for (int i = 0; i < 2; ++i)
#pragma unroll
        for (int j = 0; j < 4; ++j)
            D[(size_t)(bm * 32 + tr * 2 + i) * 64 + tc * 4 + j] = acc[i][j];
}

// out[h, boff+b] = w0[h] + P[b,h] + 0.5*(sum_r P[b,64+16h+r]^2 - D[b,h])
// one wave per batch row; fully coalesced P reads.
__global__ __launch_bounds__(256)
void fm_combine(const float* __restrict__ P, const float* __restrict__ D,
                const float* __restrict__ w0, float* __restrict__ out, int boff)
{
    const int wave = threadIdx.x >> 6, lane = threadIdx.x & 63;
    const int b = blockIdx.x * 4 + wave;
    const float* Pb = P + (size_t)b * PN;
    const float* Db = D + (size_t)b * 64;
    const int hl = lane & 15, part = lane >> 4;
#pragma unroll
    for (int hb = 0; hb < 4; ++hb) {
        const float4 v = *(const float4*)&Pb[64 + hb * 256 + hl * 16 + part * 4];
        float q = fmaf(v.x, v.x, fmaf(v.y, v.y, fmaf(v.z, v.z, v.w * v.w)));
        q += __shfl_xor(q, 16);
        q += __shfl_xor(q, 32);
        if (part == 0) {
            const int h = hb * 16 + hl;
            out[(size_t)h * BATCH_N + boff + b] = w0[h] + Pb[h] + 0.5f * (q - Db[h]);
        }
    }
}

extern "C" void kernel_launch(void* const* d_in, const int* in_sizes, int n_in,
                              void* d_out, int out_size, void* d_ws, size_t ws_size,
                              hipStream_t stream)
{
    const float* x   = (const float*)d_in[0];
    const float* W1  = (const float*)d_in[1];
    const float* b1  = (const float*)d_in[2];
    const float* W2  = (const float*)d_in[3];
    const float* b2  = (const float*)d_in[4];
    const float* W3  = (const float*)d_in[5];
    const float* b3  = (const float*)d_in[6];
    const float* fw0 = (const float*)d_in[7];
    const float* fw  = (const float*)d_in[8];
    const float* fV  = (const float*)d_in[9];
    float* out = (float*)d_out;

    const int CH = 4096;   // 2 chunks: keeps grid = 256 blocks and ws <= ~112 MB

    char* ws = (char*)d_ws;
    size_t o = 0;
    auto alloc = [&](size_t bytes) { void* p = ws + o; o += (bytes + 255) & ~(size_t)255; return p; };

    short* W1h = (short*)alloc((size_t)HIDDEN_N * IN_SIZE_N * 2);
    short* W1l = (short*)alloc((size_t)HIDDEN_N * IN_SIZE_N * 2);
    short* W2h = (short*)alloc((size_t)HIDDEN_N * HIDDEN_N * 2);
    short* W2l = (short*)alloc((size_t)HIDDEN_N * HIDDEN_N * 2);
    short* W3h = (short*)alloc((size_t)HIDDEN_N * HIDDEN_N * 2);
    short* W3l = (short*)alloc((size_t)HIDDEN_N * HIDDEN_N * 2);
    short* PBh = (short*)alloc((size_t)PN * HIDDEN_N * 2);
    short* PBl = (short*)alloc((size_t)PN * HIDDEN_N * 2);
    float* Vsq = (float*)alloc((size_t)HEADS_N * HIDDEN_N * 4);
    short* hAh = (short*)alloc((size_t)CH * HIDDEN_N * 2);
    short* hAl = (short*)alloc((size_t)CH * HIDDEN_N * 2);
    char*  hBb = (char*) alloc((size_t)CH * HIDDEN_N * 4);   // hBh+hBl contiguous
    short* hBh = (short*)hBb;
    short* hBl = hBh + (size_t)CH * HIDDEN_N;
    short* xh  = (short*)hBb;                      // alias (dead when h2/P live)
    short* xl  = xh + (size_t)CH * IN_SIZE_N;
    float* P   = (float*)hBb;                      // [CH][PN] f32, alias of hB
    float* Dg  = (float*)(hBb + (size_t)CH * PN * 4);

    const dim3 blk(256, 1, 1);
    const dim3 blk512(512, 1, 1);

    // one-time packs
    transpose_split<<<dim3(HIDDEN_N / 32, IN_SIZE_N / 32), dim3(32, 8), 0, stream>>>(W1, W1h, W1l, IN_SIZE_N, HIDDEN_N);
    transpose_split<<<dim3(HIDDEN_N / 32, HIDDEN_N / 32), dim3(32, 8), 0, stream>>>(W2, W2h, W2l, HIDDEN_N, HIDDEN_N);
    transpose_split<<<dim3(HIDDEN_N / 32, HIDDEN_N / 32), dim3(32, 8), 0, stream>>>(W3, W3h, W3l, HIDDEN_N, HIDDEN_N);
    pack_split<<<dim3(128), blk, 0, stream>>>(fw, (long)HEADS_N * HIDDEN_N, PBh, PBl, (long)HEADS_N * HIDDEN_N);
    pack_split<<<dim3(1024), blk, 0, stream>>>(fV, (long)HEADS_N * RANK_N * HIDDEN_N,
                                               PBh + (size_t)HEADS_N * HIDDEN_N,
                                               PBl + (size_t)HEADS_N * HIDDEN_N,
                                               (long)(PN - HEADS_N) * HIDDEN_N);
    fm_vsq<<<dim3(HEADS_N), blk, 0, stream>>>(fV, Vsq);

    for (int c = 0; c < 2; ++c) {
        pack_split<<<dim3(1024), blk, 0, stream>>>(x + (size_t)c * CH * IN_SIZE_N,
                                                   (long)CH * IN_SIZE_N, xh, xl, (long)CH * IN_SIZE_N);
        // h1 = tanh(x W1 + b1)
        gemm8<256, true><<<dim3((HIDDEN_N / 128) * (CH / 256)), blk512, 0, stream>>>(
            xh, xl, W1h, W1l, b1, hAh, hAl, nullptr, HIDDEN_N / 128, HIDDEN_N, IN_SIZE_N);
        // h2
        gemm8<256, true><<<dim3((HIDDEN_N / 128) * (CH / 256)), blk512, 0, stream>>>(
            hAh, hAl, W2h, W2l, b2, hBh, hBl, nullptr, HIDDEN_N / 128, HIDDEN_N, HIDDEN_N);
        // h3 (overwrites h1)
        gemm8<256, true><<<dim3((HIDDEN_N / 128) * (CH / 256)), blk512, 0, stream>>>(
            hBh, hBl, W3h, W3l, b3, hAh, hAl, nullptr, HIDDEN_N / 128, HIDDEN_N, HIDDEN_N);
        // P = h3 @ [fm_w; fm_V]^T   (f32 out, overwrites h2 region)
        gemm8<128, false><<<dim3((PN / 128) * (CH / 128)), blk512, 0, stream>>>(
            hAh, hAl, PBh, PBl, nullptr, nullptr, nullptr, P, PN / 128, PN, HIDDEN_N);
        // D = h3^2 @ Vsq^T
        gemm_diag<<<dim3(CH / 32), blk, 0, stream>>>(hAh, hAl, Vsq, Dg, HIDDEN_N);
        fm_combine<<<dim3(CH / 4), blk, 0, stream>>>(P, Dg, fw0, out, c * CH);
    }
}